// Round 1
// baseline (1726.554 us; speedup 1.0000x reference)
//
#include <hip/hip_runtime.h>
#include <cstdint>
#include <cstddef>

#define B_SZ 8192
#define H_N  8
#define K_N  4096
#define D_N  1024
#define HD_N 128

// ---------- helpers ----------
__device__ __forceinline__ unsigned int ordf(float f) {
    unsigned int u = __float_as_uint(f);
    return (u & 0x80000000u) ? ~u : (u | 0x80000000u);
}

__device__ __forceinline__ unsigned long long shfl_xor_u64(unsigned long long v, int m) {
    int lo = (int)(unsigned int)v;
    int hi = (int)(unsigned int)(v >> 32);
    lo = __shfl_xor(lo, m, 64);
    hi = __shfl_xor(hi, m, 64);
    return ((unsigned long long)(unsigned int)hi << 32) | (unsigned int)lo;
}

// ---------- kernel 1: row-wise L2 normalize (rows of 128 floats) ----------
// block = 256 threads = 4 waves; one wave per row; each lane handles 2 floats.
__global__ void norm_rows_kernel(const float* __restrict__ in,
                                 float* __restrict__ out, int nrows) {
    int wid  = (int)((blockIdx.x * blockDim.x + threadIdx.x) >> 6);
    int lane = threadIdx.x & 63;
    if (wid >= nrows) return;
    const float* r = in + (size_t)wid * HD_N;
    float2 v = *(const float2*)(r + lane * 2);
    float ss = v.x * v.x + v.y * v.y;
#pragma unroll
    for (int m = 32; m; m >>= 1) ss += __shfl_xor(ss, m, 64);
    float d = fmaxf(sqrtf(ss), 1e-12f);
    float2 o;
    o.x = v.x / d;
    o.y = v.y / d;
    *(float2*)(out + (size_t)wid * HD_N + lane * 2) = o;
}

// ---------- kernel 2: per-head fp32 GEMM (sims) + distances + atomic argmax ----
// grid = (B/128, K/128, H), block = 256.
// C tile 128x128, micro-tile 8x8/thread, BK=32 LDS staging (transposed [k][m]).
__global__ void sims_kernel(const float* __restrict__ zn,
                            const float* __restrict__ cbn,
                            float* __restrict__ dist,
                            unsigned long long* __restrict__ packed) {
    __shared__ float As[32][132];
    __shared__ float Bs[32][132];

    const int bm = blockIdx.x;
    const int bn = blockIdx.y;
    const int h  = blockIdx.z;
    const int t  = threadIdx.x;
    const int cx = t & 15;   // column (n) group — varies fastest with lane
    const int cy = t >> 4;   // row (m) group

    float acc[8][8];
#pragma unroll
    for (int i = 0; i < 8; ++i)
#pragma unroll
        for (int j = 0; j < 8; ++j) acc[i][j] = 0.f;

    const float* Ag = zn  + (size_t)(bm * 128) * D_N + h * HD_N;
    const float* Bg = cbn + ((size_t)h * K_N + (size_t)bn * 128) * HD_N;

    for (int ks = 0; ks < HD_N; ks += 32) {
        // stage 128x32 tiles of A and B, transposed into LDS [k][m]
#pragma unroll
        for (int i = 0; i < 4; ++i) {
            int fl  = t + i * 256;     // float4 index, 0..1023
            int row = fl >> 3;         // 0..127
            int kq  = fl & 7;          // 0..7 (float4 within the 32-wide k slab)
            float4 v = *(const float4*)(Ag + (size_t)row * D_N + ks + kq * 4);
            As[kq * 4 + 0][row] = v.x;
            As[kq * 4 + 1][row] = v.y;
            As[kq * 4 + 2][row] = v.z;
            As[kq * 4 + 3][row] = v.w;
            float4 w = *(const float4*)(Bg + (size_t)row * HD_N + ks + kq * 4);
            Bs[kq * 4 + 0][row] = w.x;
            Bs[kq * 4 + 1][row] = w.y;
            Bs[kq * 4 + 2][row] = w.z;
            Bs[kq * 4 + 3][row] = w.w;
        }
        __syncthreads();

#pragma unroll 8
        for (int kk = 0; kk < 32; ++kk) {
            float4 a0 = *(const float4*)&As[kk][cy * 4];
            float4 a1 = *(const float4*)&As[kk][cy * 4 + 64];
            float4 b0 = *(const float4*)&Bs[kk][cx * 4];
            float4 b1 = *(const float4*)&Bs[kk][cx * 4 + 64];
            float av[8] = {a0.x, a0.y, a0.z, a0.w, a1.x, a1.y, a1.z, a1.w};
            float bv[8] = {b0.x, b0.y, b0.z, b0.w, b1.x, b1.y, b1.z, b1.w};
#pragma unroll
            for (int i = 0; i < 8; ++i)
#pragma unroll
                for (int j = 0; j < 8; ++j)
                    acc[i][j] = fmaf(av[i], bv[j], acc[i][j]);
        }
        __syncthreads();
    }

    // epilogue: distances = 1 - sim (coalesced float4), argmax via packed u64
    const int m_base = bm * 128;
    const int n_base = bn * 128;
#pragma unroll
    for (int i = 0; i < 8; ++i) {
        int m = cy * 4 + (i & 3) + ((i >> 2) << 6);
        size_t drow = ((size_t)(m_base + m) * H_N + h) * (size_t)K_N + n_base;
        float4 d0 = make_float4(1.f - acc[i][0], 1.f - acc[i][1],
                                1.f - acc[i][2], 1.f - acc[i][3]);
        float4 d1 = make_float4(1.f - acc[i][4], 1.f - acc[i][5],
                                1.f - acc[i][6], 1.f - acc[i][7]);
        *(float4*)(dist + drow + cx * 4)      = d0;
        *(float4*)(dist + drow + cx * 4 + 64) = d1;

        unsigned long long best = 0ull;
#pragma unroll
        for (int j = 0; j < 8; ++j) {
            int n = n_base + cx * 4 + (j & 3) + ((j >> 2) << 6);
            unsigned long long p =
                ((unsigned long long)ordf(acc[i][j]) << 32) |
                (unsigned int)(K_N - 1 - n);
            best = (p > best) ? p : best;
        }
        // reduce across the 16 lanes sharing this row (same cy, cx 0..15)
#pragma unroll
        for (int ml = 1; ml < 16; ml <<= 1) {
            unsigned long long o = shfl_xor_u64(best, ml);
            best = (o > best) ? o : best;
        }
        if (cx == 0) {
            atomicMax(packed + (size_t)(m_base + m) * H_N + h, best);
        }
    }
}

// ---------- kernel 3: decode indices, gather z_q ----------
// one wave per (b,h) row.
__global__ void finalize_kernel(const unsigned long long* __restrict__ packed,
                                const float* __restrict__ z,
                                const float* __restrict__ cb,
                                float* __restrict__ zq,
                                float* __restrict__ idx_out) {
    int rid  = (int)((blockIdx.x * blockDim.x + threadIdx.x) >> 6);
    int lane = threadIdx.x & 63;
    if (rid >= B_SZ * H_N) return;
    int b = rid >> 3;
    int h = rid & 7;
    unsigned long long p = packed[rid];
    int idx = K_N - 1 - (int)(unsigned int)(p & 0xFFFFFFFFull);
    if (lane == 0) idx_out[rid] = (float)idx;
    const float* crow = cb + ((size_t)h * K_N + idx) * HD_N;
    const float* zrow = z + (size_t)b * D_N + h * HD_N;
    float2 c  = *(const float2*)(crow + lane * 2);
    float2 zr = *(const float2*)(zrow + lane * 2);
    float2 o;
    o.x = zr.x + (c.x - zr.x);  // replicate z_r + (z_q - z_r) rounding
    o.y = zr.y + (c.y - zr.y);
    *(float2*)(zq + (size_t)b * D_N + h * HD_N + lane * 2) = o;
}

extern "C" void kernel_launch(void* const* d_in, const int* in_sizes, int n_in,
                              void* d_out, int out_size, void* d_ws, size_t ws_size,
                              hipStream_t stream) {
    const float* z  = (const float*)d_in[0];   // (B, D)
    const float* cb = (const float*)d_in[1];   // (H, K, HD)

    float* out  = (float*)d_out;
    float* zq   = out;                                     // B*D floats
    float* idxo = out + (size_t)B_SZ * D_N;                // B*H floats
    float* dist = idxo + (size_t)B_SZ * H_N;               // B*H*K floats

    float* zn  = (float*)d_ws;                             // B*D floats (32 MB)
    float* cbn = zn + (size_t)B_SZ * D_N;                  // H*K*HD floats (16 MB)
    unsigned long long* packed =
        (unsigned long long*)(cbn + (size_t)H_N * K_N * HD_N); // B*H u64 (512 KB)

    hipMemsetAsync(packed, 0, (size_t)B_SZ * H_N * sizeof(unsigned long long), stream);

    norm_rows_kernel<<<(B_SZ * H_N) / 4, 256, 0, stream>>>(z, zn, B_SZ * H_N);
    norm_rows_kernel<<<(H_N * K_N) / 4, 256, 0, stream>>>(cb, cbn, H_N * K_N);

    dim3 g(B_SZ / 128, K_N / 128, H_N);
    sims_kernel<<<g, 256, 0, stream>>>(zn, cbn, dist, packed);

    finalize_kernel<<<(B_SZ * H_N) / 4, 256, 0, stream>>>(packed, z, cb, zq, idxo);
}